// Round 3
// baseline (556.057 us; speedup 1.0000x reference)
//
#include <hip/hip_runtime.h>

#define NROW 27
#define EDIM 5120
#define QKVDIM 15360
#define HD 1280

typedef __attribute__((ext_vector_type(8))) short bf16x8;
typedef __attribute__((ext_vector_type(4))) float f32x4;

__device__ inline short f2bf(float x) {
    unsigned u = __builtin_bit_cast(unsigned, x);
    u = (u + 0x7FFFu + ((u >> 16) & 1u)) >> 16;
    return (short)u;
}
__device__ inline float bf2f(short h) {
    unsigned u = ((unsigned)(unsigned short)h) << 16;
    return __builtin_bit_cast(float, u);
}

// ---------------------------------------------------------------------------
// Barrier-free streaming GEMM:
//   C_partial[ky][27][Ntot] = X[27,K] @ W[Ntot,K]^T  (bf16 hi/lo split MFMA)
// X arrives PRE-CONVERTED to bf16 hi/lo (Xhi/Xlo, row stride K) -- produced
// by colrow_kernel (node) / attn_kernel (O). Each wave loads A-fragments
// straight from the L2-hot bf16 buffers and streams W fp32 into registers
// in B-fragment layout, converting in-register. NO LDS, NO __syncthreads:
// all waits are counted vmcnt (issue order: X frags first, then next-chunk W
// prefetch -> touching X waits vmcnt(8), W prefetch stays in flight).
// Block: Ntile=128 x Mtile=32(27), KC=64/chunk, 256 thr = 4 waves,
// wave w owns n in [32w, 32w+32): 2x2 tiles of 16x16x32 MFMA.
// ---------------------------------------------------------------------------
#define KC 64

__device__ __forceinline__ void loadW8(float4* wb, const float* wq0, const float* wq1) {
    #pragma unroll
    for (int s = 0; s < 2; ++s) {
        wb[s * 2 + 0]     = *(const float4*)(wq0 + 32 * s);
        wb[s * 2 + 1]     = *(const float4*)(wq0 + 32 * s + 4);
        wb[4 + s * 2 + 0] = *(const float4*)(wq1 + 32 * s);
        wb[4 + s * 2 + 1] = *(const float4*)(wq1 + 32 * s + 4);
    }
}

__device__ __forceinline__ void gstep(
    const short* __restrict__ xh0, const short* __restrict__ xh1,
    const short* __restrict__ xl0, const short* __restrict__ xl1, bool xok1,
    const float* __restrict__ wq0, const float* __restrict__ wq1,
    int c, int nc, float4* wcur, float4* wnxt, f32x4 (&acc)[2][2])
{
    const int ko = c * KC;

    // ---- X fragment loads (issue FIRST; L2-hot bf16) ----
    bf16x8 ah0[2], ah1[2], al0[2], al1[2];
    #pragma unroll
    for (int s = 0; s < 2; ++s) {
        ah0[s] = *(const bf16x8*)(xh0 + ko + 32 * s);
        al0[s] = *(const bf16x8*)(xl0 + ko + 32 * s);
        bf16x8 h1 = {}, l1 = {};
        if (xok1) {
            h1 = *(const bf16x8*)(xh1 + ko + 32 * s);
            l1 = *(const bf16x8*)(xl1 + ko + 32 * s);
        }
        ah1[s] = h1;
        al1[s] = l1;
    }

    // ---- prefetch next W chunk (stays in flight through the MFMAs) ----
    if (c + 1 < nc) loadW8(wnxt, wq0 + (c + 1) * KC, wq1 + (c + 1) * KC);

    // ---- convert current W regs -> bf16 hi/lo B-fragments ----
    bf16x8 whi[2][2], wlo[2][2];   // [s][g]
    #pragma unroll
    for (int g = 0; g < 2; ++g) {
        #pragma unroll
        for (int s = 0; s < 2; ++s) {
            const float4 a = wcur[g * 4 + s * 2 + 0];
            const float4 b = wcur[g * 4 + s * 2 + 1];
            const float f[8] = {a.x, a.y, a.z, a.w, b.x, b.y, b.z, b.w};
            bf16x8 h8, l8;
            #pragma unroll
            for (int j = 0; j < 8; ++j) {
                short h = f2bf(f[j]);
                h8[j] = h;
                l8[j] = f2bf(f[j] - bf2f(h));
            }
            whi[s][g] = h8;
            wlo[s][g] = l8;
        }
    }

    // ---- MFMA ----
    #pragma unroll
    for (int s = 0; s < 2; ++s) {
        acc[0][0] = __builtin_amdgcn_mfma_f32_16x16x32_bf16(ah0[s], whi[s][0], acc[0][0], 0, 0, 0);
        acc[0][0] = __builtin_amdgcn_mfma_f32_16x16x32_bf16(ah0[s], wlo[s][0], acc[0][0], 0, 0, 0);
        acc[0][0] = __builtin_amdgcn_mfma_f32_16x16x32_bf16(al0[s], whi[s][0], acc[0][0], 0, 0, 0);

        acc[0][1] = __builtin_amdgcn_mfma_f32_16x16x32_bf16(ah0[s], whi[s][1], acc[0][1], 0, 0, 0);
        acc[0][1] = __builtin_amdgcn_mfma_f32_16x16x32_bf16(ah0[s], wlo[s][1], acc[0][1], 0, 0, 0);
        acc[0][1] = __builtin_amdgcn_mfma_f32_16x16x32_bf16(al0[s], whi[s][1], acc[0][1], 0, 0, 0);

        acc[1][0] = __builtin_amdgcn_mfma_f32_16x16x32_bf16(ah1[s], whi[s][0], acc[1][0], 0, 0, 0);
        acc[1][0] = __builtin_amdgcn_mfma_f32_16x16x32_bf16(ah1[s], wlo[s][0], acc[1][0], 0, 0, 0);
        acc[1][0] = __builtin_amdgcn_mfma_f32_16x16x32_bf16(al1[s], whi[s][0], acc[1][0], 0, 0, 0);

        acc[1][1] = __builtin_amdgcn_mfma_f32_16x16x32_bf16(ah1[s], whi[s][1], acc[1][1], 0, 0, 0);
        acc[1][1] = __builtin_amdgcn_mfma_f32_16x16x32_bf16(ah1[s], wlo[s][1], acc[1][1], 0, 0, 0);
        acc[1][1] = __builtin_amdgcn_mfma_f32_16x16x32_bf16(al1[s], whi[s][1], acc[1][1], 0, 0, 0);
    }
}

__global__ __launch_bounds__(256, 2)
void gemm_regw(const short* __restrict__ Xhi, const short* __restrict__ Xlo,
               const float* __restrict__ W, float* __restrict__ Cp,
               int K, int Ntot, int Kblk)
{
    const int tid = threadIdx.x;
    const int n0 = blockIdx.x * 128;
    const int k0 = blockIdx.y * Kblk;

    const int lane = tid & 63;
    const int wv   = tid >> 6;
    const int lm   = lane & 15;
    const int q8   = (lane >> 4) * 8;

    f32x4 acc[2][2] = {};

    // W fragment pointers: rows n0+32wv+lm and +16, k at k0+q8
    const float* wp0 = W + (size_t)(n0 + 32 * wv + lm) * K + k0 + q8;
    const float* wp1 = wp0 + (size_t)16 * K;

    // X fragment pointers (bf16 hi/lo, row stride K); row lm+16 may be OOB
    const bool xok1 = (lm + 16) < NROW;
    const int  r1   = xok1 ? lm + 16 : 0;
    const short* xh0 = Xhi + (size_t)lm * K + k0 + q8;
    const short* xl0 = Xlo + (size_t)lm * K + k0 + q8;
    const short* xh1 = Xhi + (size_t)r1 * K + k0 + q8;
    const short* xl1 = Xlo + (size_t)r1 * K + k0 + q8;

    float4 wA[8], wB[8];
    loadW8(wA, wp0, wp1);   // chunk 0

    const int nc = Kblk / KC;
    int c = 0;
    while (c < nc) {
        gstep(xh0, xh1, xl0, xl1, xok1, wp0, wp1, c, nc, wA, wB, acc);
        ++c;
        if (c >= nc) break;
        gstep(xh0, xh1, xl0, xl1, xok1, wp0, wp1, c, nc, wB, wA, acc);
        ++c;
    }

    const size_t base = (size_t)blockIdx.y * NROW * Ntot;
    #pragma unroll
    for (int mi = 0; mi < 2; ++mi) {
        #pragma unroll
        for (int r = 0; r < 4; ++r) {
            const int m = mi * 16 + (lane >> 4) * 4 + r;
            if (m < NROW) {
                #pragma unroll
                for (int ni = 0; ni < 2; ++ni) {
                    const int n = n0 + 32 * wv + ni * 16 + lm;
                    Cp[base + (size_t)m * Ntot + n] = acc[mi][ni][r];
                }
            }
        }
    }
}

// ---------------------------------------------------------------------------
// out[27,Ntot] = sum_ky Cp[ky] + bias [, * hertz]; optional fused adj block.
// ---------------------------------------------------------------------------
__global__ __launch_bounds__(256)
void reduce_kernel(const float* __restrict__ Cp, const float* __restrict__ bias,
                   float* __restrict__ out, int Ntot, int nky, const int* __restrict__ hz,
                   const float* __restrict__ cr, const float* __restrict__ gb,
                   float* __restrict__ adj)
{
    if (adj && blockIdx.x == gridDim.x - 1) {
        for (int t = threadIdx.x; t < NROW * NROW; t += 256) {
            const int i = t / NROW, j = t % NROW;
            float v = 0.f;
            if (i != j) {
                float z = cr[i] + cr[NROW + j] + gb[0];
                v = 1.0f / (1.0f + expf(-z));
            }
            adj[t] = v;
        }
        return;
    }
    const int idx = blockIdx.x * 256 + threadIdx.x;  // float4 index
    const int total4 = NROW * Ntot / 4;
    if (idx >= total4) return;
    float4 s = ((const float4*)Cp)[idx];
    for (int k = 1; k < nky; ++k) {
        float4 p = ((const float4*)(Cp + (size_t)k * NROW * Ntot))[idx];
        s.x += p.x; s.y += p.y; s.z += p.z; s.w += p.w;
    }
    const int n = (idx * 4) % Ntot;
    float4 b = *(const float4*)(bias + n);
    s.x += b.x; s.y += b.y; s.z += b.z; s.w += b.w;
    if (hz) {
        float h = (float)hz[0] * 0.001f;
        float sc = fminf(fmaxf(h, 0.1f), 1.0f);
        s.x *= sc; s.y *= sc; s.z *= sc; s.w *= sc;
    }
    ((float4*)out)[idx] = s;
}

// ---------------------------------------------------------------------------
// col[i] = node_flat[i]·w_n ; row[i] = hist_flat[i]·w_h.
// Blocks 0..26 (node rows) additionally emit the bf16 hi/lo copy of X for
// the barrier-free GEMM (identical f2bf quantization as before).
// ---------------------------------------------------------------------------
__global__ __launch_bounds__(256)
void colrow_kernel(const float* __restrict__ node, const float* __restrict__ hist,
                   const float* __restrict__ gw, float* __restrict__ cr,
                   short* __restrict__ XhiG, short* __restrict__ XloG)
{
    const int b = blockIdx.x;
    const bool isn = (b < NROW);
    const float* x = isn ? node + (size_t)b * EDIM : hist + (size_t)(b - NROW) * EDIM;
    const float* w = isn ? gw + EDIM : gw;
    const int tid = threadIdx.x;
    float a = 0.f;
    for (int f = tid; f < EDIM / 4; f += 256) {
        float4 xv = ((const float4*)x)[f];
        float4 wv = ((const float4*)w)[f];
        a += xv.x * wv.x + xv.y * wv.y + xv.z * wv.z + xv.w * wv.w;
        if (isn) {
            short4 h4, l4;
            h4.x = f2bf(xv.x); l4.x = f2bf(xv.x - bf2f(h4.x));
            h4.y = f2bf(xv.y); l4.y = f2bf(xv.y - bf2f(h4.y));
            h4.z = f2bf(xv.z); l4.z = f2bf(xv.z - bf2f(h4.z));
            h4.w = f2bf(xv.w); l4.w = f2bf(xv.w - bf2f(h4.w));
            *(short4*)&XhiG[(size_t)b * EDIM + 4 * f] = h4;
            *(short4*)&XloG[(size_t)b * EDIM + 4 * f] = l4;
        }
    }
    #pragma unroll
    for (int off = 32; off; off >>= 1) a += __shfl_down(a, off);
    __shared__ float red[4];
    if ((tid & 63) == 0) red[tid >> 6] = a;
    __syncthreads();
    if (tid == 0) cr[b] = red[0] + red[1] + red[2] + red[3];
}

// ---------------------------------------------------------------------------
// MHA on qkv[27, 15360] (biases already added). One block per (head, query).
// Output written directly as bf16 hi/lo (gemm2's A-operand format).
// ---------------------------------------------------------------------------
__global__ __launch_bounds__(256)
void attn_kernel(const float* __restrict__ qkv,
                 short* __restrict__ Ohi, short* __restrict__ Olo)
{
    __shared__ float qs[HD];
    __shared__ float sc[NROW];
    __shared__ float pr[NROW];
    const int bx = blockIdx.x;
    const int h = bx & 3;
    const int i = bx >> 2;
    const int tid = threadIdx.x;

    const size_t qoff = (size_t)i * QKVDIM + (size_t)h * HD;
    for (int d = tid; d < HD; d += 256) qs[d] = qkv[qoff + d];
    __syncthreads();

    const int wid = tid >> 6, lane = tid & 63;
    for (int j = wid; j < NROW; j += 4) {
        const float* kr = qkv + (size_t)j * QKVDIM + EDIM + (size_t)h * HD;
        float a = 0.f;
        #pragma unroll
        for (int it = 0; it < 5; ++it) {
            int d4 = lane + 64 * it;
            float4 k4 = *(const float4*)(kr + 4 * d4);
            float4 q4 = *(const float4*)(qs + 4 * d4);
            a += q4.x * k4.x + q4.y * k4.y + q4.z * k4.z + q4.w * k4.w;
        }
        #pragma unroll
        for (int off = 32; off; off >>= 1) a += __shfl_down(a, off);
        if (lane == 0) sc[j] = a * 0.02795084971874737f;  // 1/sqrt(1280)
    }
    __syncthreads();

    float mxv = -1e30f;
    for (int j = 0; j < NROW; ++j) mxv = fmaxf(mxv, sc[j]);
    float s = 0.f;
    for (int j = 0; j < NROW; ++j) s += expf(sc[j] - mxv);
    if (tid < NROW) pr[tid] = expf(sc[tid] - mxv) / s;
    __syncthreads();

    for (int d4 = tid; d4 < HD / 4; d4 += 256) {
        float4 o = make_float4(0.f, 0.f, 0.f, 0.f);
        for (int j = 0; j < NROW; ++j) {
            const float4 v4 = *(const float4*)(qkv + (size_t)j * QKVDIM + 2 * EDIM + (size_t)h * HD + 4 * d4);
            const float p = pr[j];
            o.x = fmaf(p, v4.x, o.x);
            o.y = fmaf(p, v4.y, o.y);
            o.z = fmaf(p, v4.z, o.z);
            o.w = fmaf(p, v4.w, o.w);
        }
        short4 h4, l4;
        h4.x = f2bf(o.x); l4.x = f2bf(o.x - bf2f(h4.x));
        h4.y = f2bf(o.y); l4.y = f2bf(o.y - bf2f(h4.y));
        h4.z = f2bf(o.z); l4.z = f2bf(o.z - bf2f(h4.z));
        h4.w = f2bf(o.w); l4.w = f2bf(o.w - bf2f(h4.w));
        const size_t off = (size_t)i * EDIM + (size_t)h * HD + 4 * d4;
        *(short4*)&Ohi[off] = h4;
        *(short4*)&Olo[off] = l4;
    }
}

extern "C" void kernel_launch(void* const* d_in, const int* in_sizes, int n_in,
                              void* d_out, int out_size, void* d_ws, size_t ws_size,
                              hipStream_t stream)
{
    const float* node = (const float*)d_in[0];
    const float* hist = (const float*)d_in[1];
    const float* gw   = (const float*)d_in[2];
    const float* gb   = (const float*)d_in[3];
    const float* inw  = (const float*)d_in[4];
    const float* inb  = (const float*)d_in[5];
    const float* outw = (const float*)d_in[6];
    const float* outb = (const float*)d_in[7];
    const int*   hz   = (const int*)d_in[8];

    float* out = (float*)d_out;  // [0:138240) attended-out, [138240:138969) adj

    // ws layout
    float* Cp1  = (float*)d_ws;                          // 8 * 27 * 15360 f
    float* qkvf = Cp1 + (size_t)8 * NROW * QKVDIM;       // 27 * 15360 f
    float* Cp2  = qkvf + (size_t)NROW * QKVDIM;          // 16 * 27 * 5120 f
    float* cr   = Cp2 + (size_t)16 * NROW * EDIM;        // 64 f (54 used)
    short* XhiG = (short*)(cr + 64);                     // 27*5120 bf16
    short* XloG = XhiG + (size_t)NROW * EDIM;
    short* OhiG = XloG + (size_t)NROW * EDIM;
    short* OloG = OhiG + (size_t)NROW * EDIM;

    colrow_kernel<<<54, 256, 0, stream>>>(node, hist, gw, cr, XhiG, XloG);

    // qkv = node_flat @ in_w.T (+bias in reduce): N=15360, ksplit=8
    gemm_regw<<<dim3(120, 8), 256, 0, stream>>>(XhiG, XloG, inw, Cp1, EDIM, QKVDIM, EDIM / 8);
    reduce_kernel<<<NROW * QKVDIM / 4 / 256, 256, 0, stream>>>(
        Cp1, inb, qkvf, QKVDIM, 8, nullptr, nullptr, nullptr, nullptr);

    attn_kernel<<<108, 256, 0, stream>>>(qkvf, OhiG, OloG);

    // out = (O @ out_w.T + out_b) * hertz: N=5120, ksplit=16; +1 block does adj
    gemm_regw<<<dim3(40, 16), 256, 0, stream>>>(OhiG, OloG, outw, Cp2, EDIM, EDIM, EDIM / 16);
    reduce_kernel<<<NROW * EDIM / 4 / 256 + 1, 256, 0, stream>>>(
        Cp2, outb, out, EDIM, 16, hz, cr, gb, out + (size_t)NROW * EDIM);
}